// Round 1
// baseline (233.387 us; speedup 1.0000x reference)
//
#include <hip/hip_runtime.h>
#include <hip/hip_bf16.h>

// ---------------- problem constants ----------------
#define B_ROWS 16384
#define NF 26
#define NV 100000
#define NK 16
#define ND 13
#define NH 400
#define IN_DIM 429   // 26*16 + 13
#define XPAD 448     // padded K for GEMM1 (28 tiles of 16)
#define EPS 1e-5f

// ---------------- ws layout (in floats) ----------------
// X  : [B][448]  padded input matrix (embeddings | dense | zeros)
// Z1 : [B][400]  pre-BN layer-1 activations
// Z2 : aliases X (X is dead after GEMM1)
// base: [B]      y_1st + fm_y per row
// stats: gsum1,gsq1,alpha1,beta1,gsum2,gsq2,alpha2,beta2 (400 each)
static const size_t X_OFF    = 0;
static const size_t X_SIZE   = (size_t)B_ROWS * XPAD;        // 7,340,032
static const size_t Z1_OFF   = X_OFF + X_SIZE;
static const size_t Z1_SIZE  = (size_t)B_ROWS * NH;          // 6,553,600
static const size_t Z2_OFF   = 0;                            // alias X
static const size_t BASE_OFF = Z1_OFF + Z1_SIZE;
static const size_t STATS_OFF = BASE_OFF + B_ROWS;
// total ~13.92M floats = ~55.7 MB

// =====================================================================
// Kernel 1: gather embeddings -> X, compute base = y_1st + fm_y
// block = 256 threads = 16 rows x 16 lanes(k)
// =====================================================================
__global__ __launch_bounds__(256) void gather_kernel(
    const int* __restrict__ Xcat, const float* __restrict__ Xdense,
    const float* __restrict__ fm1, const float* __restrict__ emb,
    const float* __restrict__ Wd, const float* __restrict__ bd,
    float* __restrict__ X, float* __restrict__ base)
{
    int tid = threadIdx.x;
    int r = blockIdx.x * 16 + (tid >> 4);
    int k = tid & 15;
    const int* idxp = Xcat + (size_t)r * NF;
    float* xrow = X + (size_t)r * XPAD;

    float s = 0.f, ss = 0.f;
    #pragma unroll
    for (int f = 0; f < NF; ++f) {
        int idx = idxp[f];
        float v = emb[((size_t)f * NV + idx) * NK + k];
        s += v; ss += v * v;
        xrow[f * NK + k] = v;
    }
    // FM 1st order: lane k covers fields k and k+16
    float fmsum = fm1[(size_t)k * NV + idxp[k]];
    if (k < NF - 16) fmsum += fm1[(size_t)(k + 16) * NV + idxp[k + 16]];
    // dense part: lane k<13 contributes x_d * Wd, and stores dense into X
    float dsum = 0.f;
    if (k < ND) {
        float xd = Xdense[(size_t)r * ND + k];
        dsum = xd * Wd[k];
        xrow[NF * NK + k] = xd;     // cols 416..428
    }
    // zero-pad cols 429..447 (19 slots)
    xrow[IN_DIM + k] = 0.f;          // 429..444
    if (k < XPAD - IN_DIM - 16) xrow[IN_DIM + 16 + k] = 0.f; // 445..447

    // FM 2nd order partial: ix_k = s^2 - sum(v^2); reduce over 16 lanes
    float ix = s * s - ss;
    float rf = fmsum, rd = dsum;
    #pragma unroll
    for (int off = 8; off; off >>= 1) {
        ix += __shfl_xor(ix, off, 16);
        rf += __shfl_xor(rf, off, 16);
        rd += __shfl_xor(rd, off, 16);
    }
    if (k == 0) base[r] = 0.5f * ix + rf + rd + bd[0];
}

// =====================================================================
// Kernel 2/3: fp32 GEMM  Z = op(A) @ W + bias, fused column-stat atomics.
// op(A) = A (stage 1) or relu(alpha*A+beta) per-column (stage 2).
// Tile 128x64, BK=16, 256 threads, 8x4 per thread.
// grid.x = 128 mblocks * 7 nblocks
// =====================================================================
template<bool APPLY_BN>
__global__ __launch_bounds__(256) void gemm_kernel(
    const float* __restrict__ A, int lda, int Ktiles, int KW,
    const float* __restrict__ W, const float* __restrict__ bias,
    const float* __restrict__ alpha, const float* __restrict__ beta,
    float* __restrict__ Z, float* __restrict__ gsum, float* __restrict__ gsq)
{
    __shared__ float a_s[16][128];
    __shared__ float b_s[16][64];
    int tid = threadIdx.x;
    int mblk = blockIdx.x & 127;        // 16384/128 = 128
    int nblk = blockIdx.x >> 7;         // 0..6
    int m0 = mblk * 128, n0 = nblk * 64;
    int tx = tid & 15, ty = tid >> 4;

    float acc[8][4] = {};

    for (int kt = 0; kt < Ktiles; ++kt) {
        int k0 = kt * 16;
        // ---- load A tile (transposed into LDS: a_s[k][m]) ----
        #pragma unroll
        for (int i = 0; i < 2; ++i) {
            int slot = tid * 2 + i;
            int m = slot >> 2, c = slot & 3;
            float4 v = *(const float4*)(A + (size_t)(m0 + m) * lda + k0 + c * 4);
            if constexpr (APPLY_BN) {
                float4 al = *(const float4*)(alpha + k0 + c * 4);
                float4 be = *(const float4*)(beta + k0 + c * 4);
                v.x = fmaxf(0.f, al.x * v.x + be.x);
                v.y = fmaxf(0.f, al.y * v.y + be.y);
                v.z = fmaxf(0.f, al.z * v.z + be.z);
                v.w = fmaxf(0.f, al.w * v.w + be.w);
            }
            a_s[c * 4 + 0][m] = v.x;
            a_s[c * 4 + 1][m] = v.y;
            a_s[c * 4 + 2][m] = v.z;
            a_s[c * 4 + 3][m] = v.w;
        }
        // ---- load B tile b_s[k][n] ----
        {
            int kk = tid >> 4;
            int n = (tid & 15) * 4;
            int gk = k0 + kk;
            float4 v = make_float4(0.f, 0.f, 0.f, 0.f);
            if (gk < KW && n0 + n < NH)
                v = *(const float4*)(W + (size_t)gk * NH + n0 + n);
            *(float4*)&b_s[kk][n] = v;
        }
        __syncthreads();
        // ---- compute ----
        #pragma unroll
        for (int k = 0; k < 16; ++k) {
            float a0[8], b0[4];
            *(float4*)&a0[0] = *(const float4*)&a_s[k][ty * 8];
            *(float4*)&a0[4] = *(const float4*)&a_s[k][ty * 8 + 4];
            *(float4*)&b0[0] = *(const float4*)&b_s[k][tx * 4];
            #pragma unroll
            for (int i = 0; i < 8; ++i)
                #pragma unroll
                for (int j = 0; j < 4; ++j)
                    acc[i][j] += a0[i] * b0[j];
        }
        __syncthreads();
    }

    // ---- epilogue: +bias, store, per-column partial stats ----
    int cbase = n0 + tx * 4;
    float bv[4] = {0.f, 0.f, 0.f, 0.f};
    if (cbase < NH) {
        bv[0] = bias[cbase]; bv[1] = bias[cbase + 1];
        bv[2] = bias[cbase + 2]; bv[3] = bias[cbase + 3];
    }
    float psum[4] = {}, psq[4] = {};
    #pragma unroll
    for (int i = 0; i < 8; ++i) {
        int row = m0 + ty * 8 + i;
        float4 ov;
        float v0 = acc[i][0] + bv[0]; psum[0] += v0; psq[0] += v0 * v0; ov.x = v0;
        float v1 = acc[i][1] + bv[1]; psum[1] += v1; psq[1] += v1 * v1; ov.y = v1;
        float v2 = acc[i][2] + bv[2]; psum[2] += v2; psq[2] += v2 * v2; ov.z = v2;
        float v3 = acc[i][3] + bv[3]; psum[3] += v3; psq[3] += v3 * v3; ov.w = v3;
        if (cbase < NH)
            *(float4*)(Z + (size_t)row * NH + cbase) = ov;
    }
    // reduce stats across the 16 ty-groups via LDS, one atomic per column
    __syncthreads();
    float* sbuf = &a_s[0][0];
    #pragma unroll
    for (int j = 0; j < 4; ++j) sbuf[(tx * 4 + j) * 16 + ty] = psum[j];
    __syncthreads();
    if (tid < 64) {
        float s = 0.f;
        #pragma unroll
        for (int t = 0; t < 16; ++t) s += sbuf[tid * 16 + t];
        if (n0 + tid < NH) atomicAdd(&gsum[n0 + tid], s);
    }
    __syncthreads();
    #pragma unroll
    for (int j = 0; j < 4; ++j) sbuf[(tx * 4 + j) * 16 + ty] = psq[j];
    __syncthreads();
    if (tid < 64) {
        float s = 0.f;
        #pragma unroll
        for (int t = 0; t < 16; ++t) s += sbuf[tid * 16 + t];
        if (n0 + tid < NH) atomicAdd(&gsq[n0 + tid], s);
    }
}

// =====================================================================
// Kernel: BN finalize -> alpha = g/sqrt(var+eps), beta = be - mean*alpha
// =====================================================================
__global__ void finalize_kernel(const float* __restrict__ gsum,
                                const float* __restrict__ gsq,
                                const float* __restrict__ g,
                                const float* __restrict__ be,
                                float* __restrict__ alpha,
                                float* __restrict__ beta)
{
    int c = blockIdx.x * blockDim.x + threadIdx.x;
    if (c < NH) {
        float mean = gsum[c] * (1.f / B_ROWS);
        float var  = gsq[c] * (1.f / B_ROWS) - mean * mean;
        float a = g[c] * rsqrtf(var + EPS);
        alpha[c] = a;
        beta[c]  = be[c] - mean * a;
    }
}

// =====================================================================
// Kernel: final  out[r] = base[r] + relu(alpha2*Z2+beta2) . W3 + b3
// one wave (64 lanes) per row, 4 rows per block
// =====================================================================
__global__ __launch_bounds__(256) void final_kernel(
    const float* __restrict__ Z2, const float* __restrict__ alpha2,
    const float* __restrict__ beta2, const float* __restrict__ W3,
    const float* __restrict__ b3, const float* __restrict__ base,
    float* __restrict__ out)
{
    int lane = threadIdx.x & 63;
    int r = blockIdx.x * 4 + (threadIdx.x >> 6);
    const float* zr = Z2 + (size_t)r * NH;
    float acc = 0.f;
    for (int i = lane; i < NH; i += 64) {
        float h = fmaxf(0.f, alpha2[i] * zr[i] + beta2[i]);
        acc += h * W3[i];
    }
    #pragma unroll
    for (int off = 32; off; off >>= 1) acc += __shfl_xor(acc, off, 64);
    if (lane == 0) out[r] = base[r] + acc + b3[0];
}

// =====================================================================
extern "C" void kernel_launch(void* const* d_in, const int* in_sizes, int n_in,
                              void* d_out, int out_size, void* d_ws, size_t ws_size,
                              hipStream_t stream)
{
    const int*   Xcat = (const int*)d_in[0];
    const float* Xd   = (const float*)d_in[1];
    const float* fm1  = (const float*)d_in[2];
    const float* emb  = (const float*)d_in[3];
    const float* Wd   = (const float*)d_in[4];
    const float* bd   = (const float*)d_in[5];
    const float* W1   = (const float*)d_in[6];
    const float* b1   = (const float*)d_in[7];
    const float* g1   = (const float*)d_in[8];
    const float* be1  = (const float*)d_in[9];
    const float* W2   = (const float*)d_in[10];
    const float* b2   = (const float*)d_in[11];
    const float* g2   = (const float*)d_in[12];
    const float* be2  = (const float*)d_in[13];
    const float* W3   = (const float*)d_in[14];
    const float* b3   = (const float*)d_in[15];

    float* ws   = (float*)d_ws;
    float* out  = (float*)d_out;
    float* X    = ws + X_OFF;
    float* Z1   = ws + Z1_OFF;
    float* Z2   = ws + Z2_OFF;           // aliases X (dead after GEMM1)
    float* base = ws + BASE_OFF;
    float* st   = ws + STATS_OFF;
    float* gsum1 = st;        float* gsq1 = st + 400;
    float* alpha1 = st + 800; float* beta1 = st + 1200;
    float* gsum2 = st + 1600; float* gsq2 = st + 2000;
    float* alpha2 = st + 2400;float* beta2 = st + 2800;

    // zero the stat accumulators (graph-capturable)
    hipMemsetAsync(st, 0, 3200 * sizeof(float), stream);

    gather_kernel<<<B_ROWS / 16, 256, 0, stream>>>(Xcat, Xd, fm1, emb, Wd, bd, X, base);

    // GEMM1: Z1 = X @ W1 + b1   (K padded to 448 = 28 tiles; W valid rows 429)
    gemm_kernel<false><<<128 * 7, 256, 0, stream>>>(
        X, XPAD, 28, IN_DIM, W1, b1, nullptr, nullptr, Z1, gsum1, gsq1);
    finalize_kernel<<<2, 256, 0, stream>>>(gsum1, gsq1, g1, be1, alpha1, beta1);

    // GEMM2: Z2 = relu(alpha1*Z1+beta1) @ W2 + b2   (K = 400 = 25 tiles)
    gemm_kernel<true><<<128 * 7, 256, 0, stream>>>(
        Z1, NH, 25, NH, W2, b2, alpha1, beta1, Z2, gsum2, gsq2);
    finalize_kernel<<<2, 256, 0, stream>>>(gsum2, gsq2, g2, be2, alpha2, beta2);

    final_kernel<<<B_ROWS / 4, 256, 0, stream>>>(Z2, alpha2, beta2, W3, b3, base, out);
}

// Round 2
// 101.396 us; speedup vs baseline: 2.3017x; 2.3017x over previous
//
#include <hip/hip_runtime.h>
#include <stdint.h>

// ---------------- problem constants ----------------
#define B_ROWS 16384
#define NF 26
#define NV 100000
#define ND 13
#define NH 400
#define XPAD 448     // GEMM1 K padded (14 tiles of 32)
#define ZPAD 416     // GEMM2 K padded (13 tiles of 32)
#define EPS 1e-5f

typedef __attribute__((ext_vector_type(8))) short short8;
typedef __attribute__((ext_vector_type(4))) float f32x4;
typedef __attribute__((ext_vector_type(4))) unsigned int uint4v;

__device__ inline float bf2f(unsigned short u) {
    union { unsigned int i; float f; } v; v.i = (unsigned int)u << 16; return v.f;
}
__device__ inline unsigned short f2bf(float f) {
    union { float f; unsigned int i; } v; v.f = f;
    unsigned int r = (v.i + 0x7fff + ((v.i >> 16) & 1)) >> 16;
    return (unsigned short)r;
}

// ---------------- ws layout (bytes, all 16B-aligned) ----------------
// X   : bf16 [16384][448]   14,680,064 B   (aliased by Z2 after GEMM1)
// Z1  : bf16 [16384][416]   13,631,488 B
// W1s : bf16 staged [14][4][448][8]  401,408 B
// W2s : bf16 staged [13][4][448][8]  372,736 B
// base: f32 [16384]
// st  : f32 [8][416] = gsum1,gsq1,gsum2,gsq2,alpha1,beta1,alpha2,beta2
#define X_OFF    0
#define Z1_OFF   14680064
#define W1S_OFF  28311552
#define W2S_OFF  28712960
#define BASE_OFF 29085696
#define ST_OFF   29151232

// =====================================================================
// prep: W [K][400] f32 -> staged bf16 [NT][4][448][8]
// element (kt,q,n,j) = W[kt*32+q*8+j][n]  (zero-padded)
// =====================================================================
__global__ __launch_bounds__(256) void prep_w(
    const float* __restrict__ W, int K,
    unsigned short* __restrict__ Wst, int nchunks)
{
    int c = blockIdx.x * 256 + threadIdx.x;
    if (c >= nchunks) return;
    int n  = c % 448;
    int q  = (c / 448) & 3;
    int kt = c / 1792;
    unsigned short o[8];
    #pragma unroll
    for (int j = 0; j < 8; ++j) {
        int k = kt * 32 + q * 8 + j;
        float v = (n < NH && k < K) ? W[(size_t)k * NH + n] : 0.f;
        o[j] = f2bf(v);
    }
    *(uint4v*)(Wst + (size_t)c * 8) = *(uint4v*)o;
}

// =====================================================================
// gather: embeddings -> X (bf16), base = y_1st + fm_y (+dense dot, fp32)
// block = 256 = 16 rows x 16 lanes(k)
// =====================================================================
__global__ __launch_bounds__(256) void gather_kernel(
    const int* __restrict__ Xcat, const float* __restrict__ Xdense,
    const float* __restrict__ fm1, const float* __restrict__ emb,
    const float* __restrict__ Wd, const float* __restrict__ bd,
    unsigned short* __restrict__ X, float* __restrict__ base)
{
    int tid = threadIdx.x;
    int r = blockIdx.x * 16 + (tid >> 4);
    int k = tid & 15;
    const int* idxp = Xcat + (size_t)r * NF;
    unsigned short* xrow = X + (size_t)r * XPAD;

    float s = 0.f, ss = 0.f;
    #pragma unroll
    for (int f = 0; f < NF; ++f) {
        int idx = idxp[f];
        float v = emb[((size_t)f * NV + idx) * 16 + k];
        s += v; ss += v * v;
        xrow[f * 16 + k] = f2bf(v);
    }
    float fmsum = fm1[(size_t)k * NV + idxp[k]];
    if (k < NF - 16) fmsum += fm1[(size_t)(k + 16) * NV + idxp[k + 16]];
    float dsum = 0.f;
    if (k < ND) {
        float xd = Xdense[(size_t)r * ND + k];
        dsum = xd * Wd[k];
        xrow[NF * 16 + k] = f2bf(xd);    // cols 416..428
    }
    xrow[429 + k] = 0;                    // 429..444
    if (k < 3) xrow[445 + k] = 0;         // 445..447

    float ix = s * s - ss;
    float rf = fmsum, rd = dsum;
    #pragma unroll
    for (int off = 8; off; off >>= 1) {
        ix += __shfl_xor(ix, off, 16);
        rf += __shfl_xor(rf, off, 16);
        rd += __shfl_xor(rd, off, 16);
    }
    if (k == 0) base[r] = 0.5f * ix + rf + rd + bd[0];
}

// =====================================================================
// MFMA GEMM: Z = op(A) @ W + bias, fused fp32 column stats.
// A bf16 [16384][LDA]; Wst staged [NT][4][448][8]; Z bf16 [16384][ldz].
// op(A) = A or relu(alpha*A+beta) applied per-K-column on A fragments.
// grid = 256 blocks (64 rows each), 4 waves, wave = 16 rows x 400 cols.
// =====================================================================
template<int NT, int LDA, bool APPLY_BN>
__global__ __launch_bounds__(256, 1) void mfma_gemm(
    const unsigned short* __restrict__ A,
    const unsigned short* __restrict__ Wst,
    const float* __restrict__ bias,
    const float* __restrict__ alpha, const float* __restrict__ beta,
    unsigned short* __restrict__ Z, int ldz,
    float* __restrict__ gsum, float* __restrict__ gsq)
{
    __shared__ unsigned short b_s[2][1792 * 8];  // [buf][(q*448+n)*8+j]  28KB each
    __shared__ float sredS[4][NH];
    __shared__ float sredQ[4][NH];

    const int tid = threadIdx.x;
    const int lane = tid & 63;
    const int wv = tid >> 6;
    const int l15 = lane & 15;
    const int qh = lane >> 4;            // 0..3
    const int m0 = blockIdx.x * 64;
    const int arow = m0 + wv * 16 + l15;

    f32x4 acc[25];
    #pragma unroll
    for (int i = 0; i < 25; ++i) acc[i] = f32x4{0.f, 0.f, 0.f, 0.f};

    // ---- staging: wave wv owns chunks [wv*448, wv*448+448), 7 instrs of 64 ----
    uint4v rg[7];
    #pragma unroll
    for (int i = 0; i < 7; ++i)
        rg[i] = *(const uint4v*)(Wst + ((size_t)(wv * 448 + i * 64 + lane)) * 8);

    short8 af_next = *(const short8*)(A + (size_t)arow * LDA + qh * 8);

    for (int kt = 0; kt < NT; ++kt) {
        __syncthreads();   // everyone done reading buf[kt&1] (iteration kt-2)
        unsigned short* db = &b_s[kt & 1][(size_t)(wv * 448 + lane) * 8];
        #pragma unroll
        for (int i = 0; i < 7; ++i) *(uint4v*)(db + (size_t)i * 64 * 8) = rg[i];
        // prefetch next tile's W chunks + A fragment (hidden under compute)
        if (kt + 1 < NT) {
            #pragma unroll
            for (int i = 0; i < 7; ++i)
                rg[i] = *(const uint4v*)(Wst + (size_t)(kt + 1) * 14336 +
                                         ((size_t)(wv * 448 + i * 64 + lane)) * 8);
        }
        short8 af = af_next;
        if (kt + 1 < NT)
            af_next = *(const short8*)(A + (size_t)arow * LDA + (kt + 1) * 32 + qh * 8);

        if constexpr (APPLY_BN) {
            const int k0 = kt * 32 + qh * 8;
            float al[8], be[8];
            *(f32x4*)&al[0] = *(const f32x4*)(alpha + k0);
            *(f32x4*)&al[4] = *(const f32x4*)(alpha + k0 + 4);
            *(f32x4*)&be[0] = *(const f32x4*)(beta + k0);
            *(f32x4*)&be[4] = *(const f32x4*)(beta + k0 + 4);
            #pragma unroll
            for (int j = 0; j < 8; ++j) {
                float f = bf2f((unsigned short)af[j]);
                f = fmaxf(0.f, al[j] * f + be[j]);
                af[j] = (short)f2bf(f);
            }
        }
        __syncthreads();   // buf[kt&1] fully staged
        const unsigned short* bb = &b_s[kt & 1][(size_t)(qh * 448 + l15) * 8];
        #pragma unroll
        for (int nn = 0; nn < 25; ++nn) {
            short8 bf = *(const short8*)(bb + nn * 128);
            acc[nn] = __builtin_amdgcn_mfma_f32_16x16x32_bf16(af, bf, acc[nn], 0, 0, 0);
        }
    }

    // ---- epilogue: +bias, bf16 store, fp32 column stats ----
    #pragma unroll
    for (int nn = 0; nn < 25; ++nn) {
        int col = nn * 16 + l15;
        float bv = bias[col];
        float ps = 0.f, pq = 0.f;
        #pragma unroll
        for (int q = 0; q < 4; ++q) {
            float v = acc[nn][q] + bv;
            ps += v; pq += v * v;
            Z[(size_t)(m0 + wv * 16 + qh * 4 + q) * ldz + col] = f2bf(v);
        }
        ps += __shfl_xor(ps, 16, 64); ps += __shfl_xor(ps, 32, 64);
        pq += __shfl_xor(pq, 16, 64); pq += __shfl_xor(pq, 32, 64);
        if (lane < 16) { sredS[wv][col] = ps; sredQ[wv][col] = pq; }
    }
    // zero-pad cols [400, ldz) so GEMM2 A-frags read clean zeros
    {
        int col = NH + l15;
        if (col < ldz) {
            #pragma unroll
            for (int q = 0; q < 4; ++q)
                Z[(size_t)(m0 + wv * 16 + qh * 4 + q) * ldz + col] = 0;
        }
    }
    __syncthreads();
    for (int c = tid; c < NH; c += 256) {
        float s = sredS[0][c] + sredS[1][c] + sredS[2][c] + sredS[3][c];
        float q = sredQ[0][c] + sredQ[1][c] + sredQ[2][c] + sredQ[3][c];
        atomicAdd(&gsum[c], s);
        atomicAdd(&gsq[c], q);
    }
}

// =====================================================================
// finalize: alpha = g/sqrt(var+eps), beta = be - mean*alpha  (tail -> 0)
// =====================================================================
__global__ void finalize_kernel(const float* __restrict__ gsum,
                                const float* __restrict__ gsq,
                                const float* __restrict__ g,
                                const float* __restrict__ be,
                                float* __restrict__ alpha,
                                float* __restrict__ beta)
{
    int c = blockIdx.x * blockDim.x + threadIdx.x;
    if (c < NH) {
        float mean = gsum[c] * (1.f / B_ROWS);
        float var  = gsq[c] * (1.f / B_ROWS) - mean * mean;
        float a = g[c] * rsqrtf(var + EPS);
        alpha[c] = a;
        beta[c]  = be[c] - mean * a;
    } else if (c < ZPAD) {
        alpha[c] = 0.f;
        beta[c]  = 0.f;
    }
}

// =====================================================================
// final: out[r] = base[r] + relu(alpha2*Z2+beta2) . W3 + b3
// =====================================================================
__global__ __launch_bounds__(256) void final_kernel(
    const unsigned short* __restrict__ Z2, const float* __restrict__ alpha2,
    const float* __restrict__ beta2, const float* __restrict__ W3,
    const float* __restrict__ b3, const float* __restrict__ base,
    float* __restrict__ out)
{
    int lane = threadIdx.x & 63;
    int r = blockIdx.x * 4 + (threadIdx.x >> 6);
    const unsigned short* zr = Z2 + (size_t)r * ZPAD;
    float acc = 0.f;
    for (int i = lane; i < NH; i += 64) {
        float h = fmaxf(0.f, alpha2[i] * bf2f(zr[i]) + beta2[i]);
        acc += h * W3[i];
    }
    #pragma unroll
    for (int off = 32; off; off >>= 1) acc += __shfl_xor(acc, off, 64);
    if (lane == 0) out[r] = base[r] + acc + b3[0];
}

// =====================================================================
extern "C" void kernel_launch(void* const* d_in, const int* in_sizes, int n_in,
                              void* d_out, int out_size, void* d_ws, size_t ws_size,
                              hipStream_t stream)
{
    const int*   Xcat = (const int*)d_in[0];
    const float* Xd   = (const float*)d_in[1];
    const float* fm1  = (const float*)d_in[2];
    const float* emb  = (const float*)d_in[3];
    const float* Wd   = (const float*)d_in[4];
    const float* bd   = (const float*)d_in[5];
    const float* W1   = (const float*)d_in[6];
    const float* b1   = (const float*)d_in[7];
    const float* g1   = (const float*)d_in[8];
    const float* be1  = (const float*)d_in[9];
    const float* W2   = (const float*)d_in[10];
    const float* b2   = (const float*)d_in[11];
    const float* g2   = (const float*)d_in[12];
    const float* be2  = (const float*)d_in[13];
    const float* W3   = (const float*)d_in[14];
    const float* b3   = (const float*)d_in[15];

    char* ws = (char*)d_ws;
    unsigned short* X   = (unsigned short*)(ws + X_OFF);
    unsigned short* Z1  = (unsigned short*)(ws + Z1_OFF);
    unsigned short* Z2  = X;   // X dead after GEMM1
    unsigned short* W1s = (unsigned short*)(ws + W1S_OFF);
    unsigned short* W2s = (unsigned short*)(ws + W2S_OFF);
    float* base = (float*)(ws + BASE_OFF);
    float* st   = (float*)(ws + ST_OFF);
    float* gsum1 = st;          float* gsq1 = st + 416;
    float* gsum2 = st + 832;    float* gsq2 = st + 1248;
    float* alpha1 = st + 1664;  float* beta1 = st + 2080;
    float* alpha2 = st + 2496;  float* beta2 = st + 2912;
    float* out = (float*)d_out;

    hipMemsetAsync(st, 0, 4 * 416 * sizeof(float), stream);

    prep_w<<<98, 256, 0, stream>>>(W1, 429, W1s, 14 * 1792);
    prep_w<<<91, 256, 0, stream>>>(W2, 400, W2s, 13 * 1792);

    gather_kernel<<<B_ROWS / 16, 256, 0, stream>>>(Xcat, Xd, fm1, emb, Wd, bd, X, base);

    mfma_gemm<14, XPAD, false><<<256, 256, 0, stream>>>(
        X, W1s, b1, nullptr, nullptr, Z1, ZPAD, gsum1, gsq1);
    finalize_kernel<<<2, 256, 0, stream>>>(gsum1, gsq1, g1, be1, alpha1, beta1);

    mfma_gemm<13, ZPAD, true><<<256, 256, 0, stream>>>(
        Z1, W2s, b2, alpha1, beta1, Z2, ZPAD, gsum2, gsq2);
    finalize_kernel<<<2, 256, 0, stream>>>(gsum2, gsq2, g2, be2, alpha2, beta2);

    final_kernel<<<B_ROWS / 4, 256, 0, stream>>>(Z2, alpha2, beta2, W3, b3, base, out);
}

// Round 3
// 83.890 us; speedup vs baseline: 2.7821x; 1.2087x over previous
//
#include <hip/hip_runtime.h>
#include <stdint.h>

// ---------------- problem constants ----------------
#define B_ROWS 16384
#define NF 26
#define NV 100000
#define ND 13
#define NH 400
#define XPAD 448     // GEMM1 K padded (14 tiles of 32)
#define ZPAD 416     // GEMM2 K padded (13 tiles of 32)
#define EPS 1e-5f

typedef __attribute__((ext_vector_type(8))) short short8;
typedef __attribute__((ext_vector_type(4))) float f32x4;
typedef __attribute__((ext_vector_type(4))) unsigned int uint4v;

__device__ inline float bf2f(unsigned short u) {
    union { unsigned int i; float f; } v; v.i = (unsigned int)u << 16; return v.f;
}
__device__ inline unsigned short f2bf(float f) {
    union { float f; unsigned int i; } v; v.f = f;
    unsigned int r = (v.i + 0x7fff + ((v.i >> 16) & 1)) >> 16;
    return (unsigned short)r;
}

// ---------------- ws layout (bytes, all 16B-aligned) ----------------
// X   : bf16 [16384][448]   14,680,064 B   (aliased by Z2 after GEMM1)
// Z1  : bf16 [16384][416]   13,631,488 B
// W1s : bf16 staged [14][4][448][8]  401,408 B
// W2s : bf16 staged [13][4][448][8]  372,736 B
// base: f32 [16384]
// st  : f32 gsum1,gsq1,gsum2,gsq2 (416 each)
#define X_OFF    0
#define Z1_OFF   14680064
#define W1S_OFF  28311552
#define W2S_OFF  28712960
#define BASE_OFF 29085696
#define ST_OFF   29151232

// =====================================================================
// gather (blocks 0..1023) + W-staging/stat-zero (blocks 1024..1212)
// gather: block = 256 = 16 rows x 16 lanes(k); emb -> X bf16, base = FM terms
// prep:   W [K][400] f32 -> staged bf16 [NT][4][448][8]:
//         element (kt,q,n,j) = W[kt*32+q*8+j][n], zero-padded
// =====================================================================
__global__ __launch_bounds__(256) void gather_prep(
    const int* __restrict__ Xcat, const float* __restrict__ Xdense,
    const float* __restrict__ fm1, const float* __restrict__ emb,
    const float* __restrict__ Wd, const float* __restrict__ bd,
    const float* __restrict__ W1, const float* __restrict__ W2,
    unsigned short* __restrict__ X, float* __restrict__ base,
    unsigned short* __restrict__ W1s, unsigned short* __restrict__ W2s,
    float* __restrict__ st)
{
    int tid = threadIdx.x;
    if (blockIdx.x >= 1024) {
        // ---------- prep path ----------
        int c = (blockIdx.x - 1024) * 256 + tid;     // 0..48383
        if (c < 256) {
            // zero stat accumulators (1664 floats)
            for (int i = tid; i < 1664; i += 256) st[i] = 0.f;
        }
        const float* W; unsigned short* dst; int K; int cc;
        if (c < 25088) { W = W1; dst = W1s; K = 429; cc = c; }
        else           { W = W2; dst = W2s; K = 400; cc = c - 25088; }
        int n  = cc % 448;
        int q  = (cc / 448) & 3;
        int kt = cc / 1792;
        unsigned short o[8];
        #pragma unroll
        for (int j = 0; j < 8; ++j) {
            int k = kt * 32 + q * 8 + j;
            float v = (n < NH && k < K) ? W[(size_t)k * NH + n] : 0.f;
            o[j] = f2bf(v);
        }
        *(uint4v*)(dst + (size_t)cc * 8) = *(uint4v*)o;
        return;
    }
    // ---------- gather path ----------
    int r = blockIdx.x * 16 + (tid >> 4);
    int k = tid & 15;
    const int* idxp = Xcat + (size_t)r * NF;
    unsigned short* xrow = X + (size_t)r * XPAD;

    float s = 0.f, ss = 0.f;
    #pragma unroll
    for (int f = 0; f < NF; ++f) {
        int idx = idxp[f];
        float v = emb[((size_t)f * NV + idx) * 16 + k];
        s += v; ss += v * v;
        xrow[f * 16 + k] = f2bf(v);
    }
    float fmsum = fm1[(size_t)k * NV + idxp[k]];
    if (k < NF - 16) fmsum += fm1[(size_t)(k + 16) * NV + idxp[k + 16]];
    float dsum = 0.f;
    if (k < ND) {
        float xd = Xdense[(size_t)r * ND + k];
        dsum = xd * Wd[k];
        xrow[NF * 16 + k] = f2bf(xd);    // cols 416..428
    }
    xrow[429 + k] = 0;                    // 429..444
    if (k < 3) xrow[445 + k] = 0;         // 445..447

    float ix = s * s - ss;
    float rf = fmsum, rd = dsum;
    #pragma unroll
    for (int off = 8; off; off >>= 1) {
        ix += __shfl_xor(ix, off, 16);
        rf += __shfl_xor(rf, off, 16);
        rd += __shfl_xor(rd, off, 16);
    }
    if (k == 0) base[r] = 0.5f * ix + rf + rd + bd[0];
}

// =====================================================================
// MFMA GEMM: Z = op(A) @ W + bias, fused fp32 column stats.
// A bf16 [16384][LDA]; Wst staged [NT][4][448][8]; Z bf16 [16384][ldz].
// If APPLY_BN: finalize BN from (gsumIn,gsqIn,g,be) into LDS alpha/beta,
// then op(A) = relu(alpha*A+beta) per-K-column on A fragments.
// grid = 256 blocks x 512 threads. 8 waves: wave wv -> rows (wv&3)*16..+15,
// N-half (wv>>2): cols 0..207 (13 frags) or 208..399 (12 frags).
// =====================================================================
template<int NT, int LDA, bool APPLY_BN>
__global__ __launch_bounds__(512, 2) void mfma_gemm(
    const unsigned short* __restrict__ A,
    const unsigned short* __restrict__ Wst,
    const float* __restrict__ bias,
    const float* __restrict__ gsumIn, const float* __restrict__ gsqIn,
    const float* __restrict__ g, const float* __restrict__ be,
    unsigned short* __restrict__ Z, int ldz,
    float* __restrict__ gsum, float* __restrict__ gsq)
{
    __shared__ unsigned short b_s[2][1792 * 8];   // 57,344 B
    __shared__ float sredS[4][416];               // 6,656 B
    __shared__ float sredQ[4][416];               // 6,656 B
    __shared__ float alpha_s[416], beta_s[416];   // 3,328 B

    const int tid = threadIdx.x;
    const int lane = tid & 63;
    const int wv = tid >> 6;             // 0..7
    const int rowgrp = wv & 3;
    const int nhalf = wv >> 2;
    const int l15 = lane & 15;
    const int qh = lane >> 4;            // 0..3
    const int m0 = blockIdx.x * 64;
    const int arow = m0 + rowgrp * 16 + l15;
    const int c0 = nhalf * 208;
    const int NFRAG = nhalf ? 12 : 13;

    if constexpr (APPLY_BN) {
        for (int c = tid; c < ZPAD; c += 512) {
            float a = 0.f, b = 0.f;
            if (c < NH) {
                float mean = gsumIn[c] * (1.f / B_ROWS);
                float var  = gsqIn[c] * (1.f / B_ROWS) - mean * mean;
                a = g[c] * rsqrtf(var + EPS);
                b = be[c] - mean * a;
            }
            alpha_s[c] = a; beta_s[c] = b;
        }
    }

    f32x4 acc[13];
    #pragma unroll
    for (int i = 0; i < 13; ++i) acc[i] = f32x4{0.f, 0.f, 0.f, 0.f};

    // W-tile staging regs: 1792 chunks of 16B per tile, 512 threads -> 3.5/thread
    uint4v rg[4];
    #pragma unroll
    for (int i = 0; i < 4; ++i) {
        int c = i * 512 + tid;
        if (c < 1792) rg[i] = *(const uint4v*)(Wst + (size_t)c * 8);
    }
    short8 af_next = *(const short8*)(A + (size_t)arow * LDA + qh * 8);

    for (int kt = 0; kt < NT; ++kt) {
        __syncthreads();   // buf[kt&1] free (last read in iter kt-2)
        #pragma unroll
        for (int i = 0; i < 4; ++i) {
            int c = i * 512 + tid;
            if (c < 1792) *(uint4v*)(&b_s[kt & 1][(size_t)c * 8]) = rg[i];
        }
        if (kt + 1 < NT) {
            #pragma unroll
            for (int i = 0; i < 4; ++i) {
                int c = i * 512 + tid;
                if (c < 1792)
                    rg[i] = *(const uint4v*)(Wst + (size_t)(kt + 1) * 14336 + (size_t)c * 8);
            }
        }
        short8 af = af_next;
        if (kt + 1 < NT)
            af_next = *(const short8*)(A + (size_t)arow * LDA + (kt + 1) * 32 + qh * 8);

        if constexpr (APPLY_BN) {
            const int k0 = kt * 32 + qh * 8;
            #pragma unroll
            for (int j = 0; j < 8; ++j) {
                float f = bf2f((unsigned short)af[j]);
                f = fmaxf(0.f, alpha_s[k0 + j] * f + beta_s[k0 + j]);
                af[j] = (short)f2bf(f);
            }
        }
        __syncthreads();   // buf[kt&1] fully staged
        const unsigned short* bb = &b_s[kt & 1][(size_t)(qh * 448 + c0 + l15) * 8];
        #pragma unroll
        for (int nn = 0; nn < 13; ++nn) {
            if (nn < NFRAG) {
                short8 bf = *(const short8*)(bb + nn * 128);
                acc[nn] = __builtin_amdgcn_mfma_f32_16x16x32_bf16(af, bf, acc[nn], 0, 0, 0);
            }
        }
    }

    // ---- epilogue: +bias, bf16 store, fp32 column stats ----
    #pragma unroll
    for (int nn = 0; nn < 13; ++nn) {
        if (nn < NFRAG) {
            int col = c0 + nn * 16 + l15;
            float bv = bias[col];
            float ps = 0.f, pq = 0.f;
            #pragma unroll
            for (int q = 0; q < 4; ++q) {
                float v = acc[nn][q] + bv;
                ps += v; pq += v * v;
                Z[(size_t)(m0 + rowgrp * 16 + qh * 4 + q) * ldz + col] = f2bf(v);
            }
            ps += __shfl_xor(ps, 16, 64); ps += __shfl_xor(ps, 32, 64);
            pq += __shfl_xor(pq, 16, 64); pq += __shfl_xor(pq, 32, 64);
            if (lane < 16) { sredS[rowgrp][col] = ps; sredQ[rowgrp][col] = pq; }
        }
    }
    // zero-pad cols [400, ldz) (waves 4-7 cover all 64 rows via rowgrp)
    if (nhalf == 1) {
        int col = NH + l15;
        if (col < ldz) {
            #pragma unroll
            for (int q = 0; q < 4; ++q)
                Z[(size_t)(m0 + rowgrp * 16 + qh * 4 + q) * ldz + col] = 0;
        }
    }
    __syncthreads();
    for (int c = tid; c < NH; c += 512) {
        float s = sredS[0][c] + sredS[1][c] + sredS[2][c] + sredS[3][c];
        float q = sredQ[0][c] + sredQ[1][c] + sredQ[2][c] + sredQ[3][c];
        atomicAdd(&gsum[c], s);
        atomicAdd(&gsq[c], q);
    }
}

// =====================================================================
// final: finalize BN2 in-block, then out[r] = base[r] + relu(.)·W3 + b3
// grid = 512 blocks x 256 threads, 32 rows/block, lane owns 8 cols.
// =====================================================================
__global__ __launch_bounds__(256) void final_kernel(
    const unsigned short* __restrict__ Z2,
    const float* __restrict__ gsum2, const float* __restrict__ gsq2,
    const float* __restrict__ g2, const float* __restrict__ be2,
    const float* __restrict__ W3, const float* __restrict__ b3,
    const float* __restrict__ base, float* __restrict__ out)
{
    __shared__ float a2s[NH], b2s[NH], w3s[NH];
    int tid = threadIdx.x;
    for (int c = tid; c < NH; c += 256) {
        float mean = gsum2[c] * (1.f / B_ROWS);
        float var  = gsq2[c] * (1.f / B_ROWS) - mean * mean;
        float a = g2[c] * rsqrtf(var + EPS);
        a2s[c] = a;
        b2s[c] = be2[c] - mean * a;
        w3s[c] = W3[c];
    }
    __syncthreads();
    int lane = tid & 63;
    int wv = tid >> 6;
    bool act = lane < 50;                 // 50*8 = 400 cols
    int cb = lane * 8;
    float al[8], bb[8], w3[8];
    #pragma unroll
    for (int j = 0; j < 8; ++j) {
        al[j] = act ? a2s[cb + j] : 0.f;
        bb[j] = act ? b2s[cb + j] : 0.f;
        w3[j] = act ? w3s[cb + j] : 0.f;
    }
    int r0 = blockIdx.x * 32 + wv * 8;
    float bias3 = b3[0];
    for (int t = 0; t < 8; t += 2) {
        int r = r0 + t;
        float acc0 = 0.f, acc1 = 0.f;
        if (act) {
            short8 z0 = *(const short8*)(Z2 + (size_t)r * ZPAD + cb);
            short8 z1 = *(const short8*)(Z2 + (size_t)(r + 1) * ZPAD + cb);
            #pragma unroll
            for (int j = 0; j < 8; ++j) {
                acc0 += fmaxf(0.f, al[j] * bf2f((unsigned short)z0[j]) + bb[j]) * w3[j];
                acc1 += fmaxf(0.f, al[j] * bf2f((unsigned short)z1[j]) + bb[j]) * w3[j];
            }
        }
        #pragma unroll
        for (int off = 32; off; off >>= 1) {
            acc0 += __shfl_xor(acc0, off, 64);
            acc1 += __shfl_xor(acc1, off, 64);
        }
        if (lane == 0) out[r] = base[r] + acc0 + bias3;
        if (lane == 1) out[r + 1] = base[r + 1] + acc1 + bias3;
    }
}

// =====================================================================
extern "C" void kernel_launch(void* const* d_in, const int* in_sizes, int n_in,
                              void* d_out, int out_size, void* d_ws, size_t ws_size,
                              hipStream_t stream)
{
    const int*   Xcat = (const int*)d_in[0];
    const float* Xd   = (const float*)d_in[1];
    const float* fm1  = (const float*)d_in[2];
    const float* emb  = (const float*)d_in[3];
    const float* Wd   = (const float*)d_in[4];
    const float* bd   = (const float*)d_in[5];
    const float* W1   = (const float*)d_in[6];
    const float* b1   = (const float*)d_in[7];
    const float* g1   = (const float*)d_in[8];
    const float* be1  = (const float*)d_in[9];
    const float* W2   = (const float*)d_in[10];
    const float* b2   = (const float*)d_in[11];
    const float* g2   = (const float*)d_in[12];
    const float* be2  = (const float*)d_in[13];
    const float* W3   = (const float*)d_in[14];
    const float* b3   = (const float*)d_in[15];

    char* ws = (char*)d_ws;
    unsigned short* X   = (unsigned short*)(ws + X_OFF);
    unsigned short* Z1  = (unsigned short*)(ws + Z1_OFF);
    unsigned short* Z2  = X;   // X dead after GEMM1
    unsigned short* W1s = (unsigned short*)(ws + W1S_OFF);
    unsigned short* W2s = (unsigned short*)(ws + W2S_OFF);
    float* base = (float*)(ws + BASE_OFF);
    float* st   = (float*)(ws + ST_OFF);
    float* gsum1 = st;          float* gsq1 = st + 416;
    float* gsum2 = st + 832;    float* gsq2 = st + 1248;
    float* out = (float*)d_out;

    // 1: gather + W staging + stats zero (1024 gather blocks + 189 prep blocks)
    gather_prep<<<1213, 256, 0, stream>>>(Xcat, Xd, fm1, emb, Wd, bd, W1, W2,
                                          X, base, W1s, W2s, st);

    // 2: Z1 = X @ W1 + b1, stats1
    mfma_gemm<14, XPAD, false><<<256, 512, 0, stream>>>(
        X, W1s, b1, nullptr, nullptr, nullptr, nullptr, Z1, ZPAD, gsum1, gsq1);

    // 3: Z2 = relu(bn1(Z1)) @ W2 + b2, stats2  (finalize1 fused in prologue)
    mfma_gemm<13, ZPAD, true><<<256, 512, 0, stream>>>(
        Z1, W2s, b2, gsum1, gsq1, g1, be1, Z2, ZPAD, gsum2, gsq2);

    // 4: out = base + relu(bn2(Z2))·W3 + b3  (finalize2 fused in prologue)
    final_kernel<<<512, 256, 0, stream>>>(Z2, gsum2, gsq2, g2, be2, W3, b3, base, out);
}